// Round 2
// baseline (111.756 us; speedup 1.0000x reference)
//
#include <hip/hip_runtime.h>
#include <hip/hip_bf16.h>
#include <math.h>

#define BB 32
#define NP 576
#define WW 32
#define DD 256
// GEMM view: M = 32*576 = 18432, N = 32*32 = 1024, K = 256.
// M tiled as 96 contiguous 192-row tiles (gcd(192,576)=192 -> every image is
// exactly 3 whole tiles, no boundary-crossing tiles). N-tiles: 8 x 128.
// Grid = 96*8 = 768 = exactly 3 blocks/CU on 256 CUs -> single scheduling
// round, no tail (previous 128-row tiling gave 1152 blocks = 1.5 rounds).

typedef __bf16 bf16x8 __attribute__((ext_vector_type(8)));
typedef float f32x4 __attribute__((ext_vector_type(4)));

__device__ __forceinline__ unsigned short f2bf(float f) {
  unsigned int u = __float_as_uint(f);
  u += 0x7FFFu + ((u >> 16) & 1u);
  return (unsigned short)(u >> 16);
}

// Kernel A: fused L2-normalize + bf16 cast. One wave per row of 256 floats.
// Also zeroes the completion counter used by the fused reduce+loss kernel
// (stream order guarantees this lands before kernel C runs).
__global__ __launch_bounds__(256) void norm_cast_kernel(
    const float* __restrict__ img, const float* __restrict__ con,
    unsigned short* __restrict__ img_bf, unsigned short* __restrict__ con_bf,
    int* __restrict__ cnt) {
  if (blockIdx.x == 0 && threadIdx.x == 0) *cnt = 0;
  int row = blockIdx.x * 4 + (threadIdx.x >> 6);
  int lane = threadIdx.x & 63;
  const int n_img = BB * NP;  // 18432 rows
  const float* src;
  unsigned short* dst;
  if (row < n_img) {
    src = img + (size_t)row * DD;
    dst = img_bf + (size_t)row * DD;
  } else {
    int r2 = row - n_img;
    src = con + (size_t)r2 * DD;
    dst = con_bf + (size_t)r2 * DD;
  }
  float4 v = ((const float4*)src)[lane];
  float ss = v.x * v.x + v.y * v.y + v.z * v.z + v.w * v.w;
  #pragma unroll
  for (int off = 1; off < 64; off <<= 1) ss += __shfl_xor(ss, off);
  float inv = 1.0f / fmaxf(sqrtf(ss), 1e-12f);
  ushort4 o;
  o.x = f2bf(v.x * inv);
  o.y = f2bf(v.y * inv);
  o.z = f2bf(v.z * inv);
  o.w = f2bf(v.w * inv);
  ((ushort4*)dst)[lane] = o;
}

// Kernel B: 192x128-tile GEMM (K=256, BK=64) with fused max-over-rows epilogue.
// Staging via global_load_lds width=16, linear LDS dest + pre-swizzled global
// source segment (seg ^ (row&7)) so ds_read_b128 fragment reads are
// conflict-free (same involution on both sides, m173/m201 pattern).
//   A-frag: lane(q=lane>>4, r=lane&15) holds A[row=r][k=q*8+j]
//   D-frag: lane holds D[row=q*4+reg][col=r]
// Each M-tile lies entirely inside image bm/3 -> P[bm][col], no crossing.
__global__ __launch_bounds__(256, 3) void gemm_max_kernel(
    const unsigned short* __restrict__ img_bf,  // 18432 x 256
    const unsigned short* __restrict__ con_bf,  // 1024 x 256
    float* __restrict__ P) {                    // [96][1024] partial maxes
  int bx = blockIdx.x;
  int bw = bx & 7;    // N-tile 0..7
  int bm = bx >> 3;   // M-tile 0..95
  int R0 = bm * 192;  // global row base (all 192 rows valid)
  int w0 = bw * 128;

  __shared__ __align__(16) unsigned char lds[41984];
  unsigned char* ldsA = lds;            // 192*128 = 24 KB
  unsigned char* ldsB = lds + 24576;    // 128*128 = 16 KB
  float* sm = (float*)(lds + 40960);    // 2 x 128 floats

  int tid = threadIdx.x;
  int wid = tid >> 6;
  int lane = tid & 63;
  int q = lane >> 4;   // 0..3
  int r = lane & 15;   // 0..15
  int wp = wid >> 1;   // row-half 0..1 (96 rows each)
  int wc = wid & 1;    // col-half 0..1 (64 cols each)

  f32x4 acc[6][4];
  #pragma unroll
  for (int i = 0; i < 6; ++i)
    #pragma unroll
    for (int j = 0; j < 4; ++j) acc[i][j] = (f32x4){0.f, 0.f, 0.f, 0.f};

  for (int kb = 0; kb < 4; ++kb) {
    __syncthreads();  // previous chunk fully consumed before overwrite
    // Stage A (192x64 bf16 = 24 KB, 6 rounds) + B (128x64 = 16 KB, 4 rounds).
    #pragma unroll
    for (int j = 0; j < 6; ++j) {
      int g = j * 256 + wid * 64 + lane;  // 0..1535
      int row = g >> 3;                   // 0..191
      int sl = (g & 7) ^ (row & 7);       // pre-swizzled 16B segment
      const unsigned short* ga = img_bf + (size_t)(R0 + row) * DD + kb * 64 + sl * 8;
      unsigned char* la = ldsA + (j * 256 + wid * 64) * 16;  // wave-uniform
      __builtin_amdgcn_global_load_lds(
          (const __attribute__((address_space(1))) unsigned int*)ga,
          (__attribute__((address_space(3))) unsigned int*)la, 16, 0, 0);
    }
    #pragma unroll
    for (int j = 0; j < 4; ++j) {
      int g = j * 256 + wid * 64 + lane;  // 0..1023
      int row = g >> 3;                   // 0..127
      int sl = (g & 7) ^ (row & 7);
      const unsigned short* gb = con_bf + (size_t)(w0 + row) * DD + kb * 64 + sl * 8;
      unsigned char* lb = ldsB + (j * 256 + wid * 64) * 16;
      __builtin_amdgcn_global_load_lds(
          (const __attribute__((address_space(1))) unsigned int*)gb,
          (__attribute__((address_space(3))) unsigned int*)lb, 16, 0, 0);
    }
    __syncthreads();  // compiler drains vmcnt(0) before the barrier
    #pragma unroll
    for (int kk = 0; kk < 2; ++kk) {
      int sw = ((((kk << 2) | q) ^ (r & 7)) << 4);
      bf16x8 bfr[4];
      #pragma unroll
      for (int wj = 0; wj < 4; ++wj) {
        int brow = wc * 64 + wj * 16 + r;
        bfr[wj] = *(const bf16x8*)(ldsB + brow * 128 + sw);
      }
      // A-fragment loaded one row-tile at a time to cap live VGPRs
      // (acc 96 + bfr 16 + af 4 ~= 120 live, fits 3 waves/EU budget of 170).
      #pragma unroll
      for (int pi = 0; pi < 6; ++pi) {
        int arow = wp * 96 + pi * 16 + r;
        bf16x8 af = *(const bf16x8*)(ldsA + arow * 128 + sw);
        #pragma unroll
        for (int wj = 0; wj < 4; ++wj)
          acc[pi][wj] =
              __builtin_amdgcn_mfma_f32_16x16x32_bf16(af, bfr[wj], acc[pi][wj], 0, 0, 0);
      }
    }
  }

  // Epilogue: max over this wave's 96 rows for each of its 64 cols.
  float mxw[4];
  #pragma unroll
  for (int wj = 0; wj < 4; ++wj) {
    float v = -1e30f;
    #pragma unroll
    for (int pi = 0; pi < 6; ++pi) {
      v = fmaxf(v, fmaxf(fmaxf(acc[pi][wj][0], acc[pi][wj][1]),
                         fmaxf(acc[pi][wj][2], acc[pi][wj][3])));
    }
    v = fmaxf(v, __shfl_xor(v, 16));
    v = fmaxf(v, __shfl_xor(v, 32));
    mxw[wj] = v;
  }
  __syncthreads();
  if (lane < 16) {
    #pragma unroll
    for (int wj = 0; wj < 4; ++wj)
      sm[wp * 128 + wc * 64 + wj * 16 + lane] = mxw[wj];
  }
  __syncthreads();
  if (tid < 128) {
    float v = fmaxf(sm[tid], sm[128 + tid]);
    P[(size_t)bm * 1024 + w0 + tid] = v;
  }
}

// Kernel C: reduce partial maxes over the 3 tile-slots of each image, masked
// mean over valid concepts -> sims; the LAST block (device-scope atomic
// counter, release/acquire threadfences) folds sims into the SigLIP loss.
__global__ __launch_bounds__(256) void reduce_loss_kernel(
    const float* __restrict__ P, const int* __restrict__ lengths,
    const float* __restrict__ lscale, const float* __restrict__ lbias,
    float* __restrict__ sims, int* __restrict__ cnt, float* __restrict__ out) {
  int tid = threadIdx.x;
  int pair = blockIdx.x * 4 + (tid >> 6);  // 0..1023
  int lane = tid & 63;
  int m = pair >> 5;
  int c = pair & 31;
  int w = lane & 31;
  const float* base = P + (size_t)(m * 3) * 1024 + c * 32 + w;
  float v = fmaxf(fmaxf(base[0], base[1024]), base[2048]);
  int len = lengths[c];
  float contrib = (w < len) ? v : 0.0f;
  #pragma unroll
  for (int off = 1; off < 32; off <<= 1) contrib += __shfl_xor(contrib, off);
  if (lane == 0) sims[pair] = contrib / (float)len;

  // --- last-block loss fold ---
  __threadfence();   // release our sims writes to device scope
  __syncthreads();   // all 4 pairs of this block written
  __shared__ int lastflag;
  if (tid == 0) lastflag = (atomicAdd(cnt, 1) == gridDim.x - 1) ? 1 : 0;
  __syncthreads();
  if (!lastflag) return;
  __threadfence();   // acquire: make all blocks' sims visible

  float tt = expf(fminf(fmaxf(lscale[0], -10.0f), 10.0f));
  float bias = lbias[0];
  float acc = 0.0f;
  for (int p = tid; p < BB * BB; p += 256) {
    int mm = p >> 5;
    int cc = p & 31;
    float lg = fminf(fmaxf(tt * sims[p] + bias, -50.0f), 50.0f);
    float x = (mm == cc) ? lg : -lg;
    float ls = (x >= 0.0f) ? -log1pf(expf(-x)) : (x - log1pf(expf(x)));
    acc += ls;
  }
  #pragma unroll
  for (int off = 1; off < 64; off <<= 1) acc += __shfl_xor(acc, off);
  __shared__ float s[4];
  if ((tid & 63) == 0) s[tid >> 6] = acc;
  __syncthreads();
  if (tid == 0) out[0] = -(s[0] + s[1] + s[2] + s[3]) / (float)(BB * BB);
}

extern "C" void kernel_launch(void* const* d_in, const int* in_sizes, int n_in,
                              void* d_out, int out_size, void* d_ws, size_t ws_size,
                              hipStream_t stream) {
  const float* img = (const float*)d_in[0];  // (32, 576, 256) f32
  const float* con = (const float*)d_in[1];  // (32, 32, 256) f32
  const int* lens = (const int*)d_in[2];     // (32,) i32
  const float* lsc = (const float*)d_in[3];  // (1,)
  const float* lbi = (const float*)d_in[4];  // (1,)

  unsigned short* img_bf = (unsigned short*)d_ws;              // 18432*256 bf16
  unsigned short* con_bf = img_bf + (size_t)BB * NP * DD;      // 1024*256 bf16
  float* P = (float*)(con_bf + (size_t)BB * WW * DD);          // 96*1024 f32
  float* sims = P + (size_t)96 * 1024;                         // 1024 f32
  int* cnt = (int*)(sims + 1024);                              // 1 i32

  norm_cast_kernel<<<(BB * NP + BB * WW) / 4, 256, 0, stream>>>(img, con, img_bf, con_bf, cnt);
  gemm_max_kernel<<<96 * 8, 256, 0, stream>>>(img_bf, con_bf, P);
  reduce_loss_kernel<<<256, 256, 0, stream>>>(P, lens, lsc, lbi, sims, cnt, (float*)d_out);
}

// Round 3
// 104.119 us; speedup vs baseline: 1.0733x; 1.0733x over previous
//
#include <hip/hip_runtime.h>
#include <hip/hip_bf16.h>
#include <math.h>

#define BB 32
#define NP 576
#define WW 32
#define DD 256
// GEMM view: M = 32*576 = 18432, N = 32*32 = 1024, K = 256.
// M is tiled as 144 contiguous 128-row tiles (image boundaries handled in the
// epilogue: gcd(128,576)=64 so a crossing tile always splits at local row 64,
// i.e. exactly at the wp wave split). N-tiles: 8 x 128.
// Launch-overhead model (round-2 inference): ~7 us per kernel launch dominates
// the non-fill window -> pipeline is A + B + fused(C,D) = 3 launches.

typedef __bf16 bf16x8 __attribute__((ext_vector_type(8)));
typedef float f32x4 __attribute__((ext_vector_type(4)));

__device__ __forceinline__ unsigned short f2bf(float f) {
  unsigned int u = __float_as_uint(f);
  u += 0x7FFFu + ((u >> 16) & 1u);
  return (unsigned short)(u >> 16);
}

// Kernel A: fused L2-normalize + bf16 cast. One wave per row of 256 floats.
// Also zeroes the completion counter used by the fused reduce+loss kernel
// (stream order guarantees this lands before that kernel runs).
__global__ __launch_bounds__(256) void norm_cast_kernel(
    const float* __restrict__ img, const float* __restrict__ con,
    unsigned short* __restrict__ img_bf, unsigned short* __restrict__ con_bf,
    int* __restrict__ cnt) {
  if (blockIdx.x == 0 && threadIdx.x == 0) *cnt = 0;
  int row = blockIdx.x * 4 + (threadIdx.x >> 6);
  int lane = threadIdx.x & 63;
  const int n_img = BB * NP;  // 18432 rows
  const float* src;
  unsigned short* dst;
  if (row < n_img) {
    src = img + (size_t)row * DD;
    dst = img_bf + (size_t)row * DD;
  } else {
    int r2 = row - n_img;
    src = con + (size_t)r2 * DD;
    dst = con_bf + (size_t)r2 * DD;
  }
  float4 v = ((const float4*)src)[lane];
  float ss = v.x * v.x + v.y * v.y + v.z * v.z + v.w * v.w;
  #pragma unroll
  for (int off = 1; off < 64; off <<= 1) ss += __shfl_xor(ss, off);
  float inv = 1.0f / fmaxf(sqrtf(ss), 1e-12f);
  ushort4 o;
  o.x = f2bf(v.x * inv);
  o.y = f2bf(v.y * inv);
  o.z = f2bf(v.z * inv);
  o.w = f2bf(v.w * inv);
  ((ushort4*)dst)[lane] = o;
}

// Kernel B: 128x128-tile GEMM (K=256, BK=64) with fused max-over-rows epilogue.
// EXACT revert to the round-1 version (proven 95.1 us pipeline; the round-2
// BM=192 variant needed 96 acc VGPRs under the (256,3) cap of ~168 and almost
// certainly spilled). Staging via global_load_lds width=16 with pre-swizzled
// global source (m173 pattern); ds_read side conflict-free.
//   A-frag: lane(q=lane>>4, r=lane&15) holds A[row=r][k=q*8+j]
//   D-frag: lane holds D[row=q*4+reg][col=r]
__global__ __launch_bounds__(256, 3) void gemm_max_kernel(
    const unsigned short* __restrict__ img_bf,  // 18432 x 256
    const unsigned short* __restrict__ con_bf,  // 1024 x 256
    float* __restrict__ P) {                    // [160][1024] partial maxes
  int bx = blockIdx.x;
  int bw = bx & 7;    // N-tile 0..7
  int bm = bx >> 3;   // M-tile 0..143
  int R0 = bm * 128;  // global row base (all 128 rows valid)
  int w0 = bw * 128;

  __shared__ __align__(16) unsigned char lds[33 * 1024];
  unsigned char* ldsA = lds;            // 16 KB
  unsigned char* ldsB = lds + 16384;    // 16 KB
  float* sm = (float*)(lds + 32768);    // 2 x 128 floats

  int tid = threadIdx.x;
  int wid = tid >> 6;
  int lane = tid & 63;
  int q = lane >> 4;   // 0..3
  int r = lane & 15;   // 0..15
  int wp = wid >> 1;   // row-half 0..1 (64 rows each)
  int wc = wid & 1;    // col-half 0..1 (64 cols each)

  f32x4 acc[4][4];
  #pragma unroll
  for (int i = 0; i < 4; ++i)
    #pragma unroll
    for (int j = 0; j < 4; ++j) acc[i][j] = (f32x4){0.f, 0.f, 0.f, 0.f};

  for (int kb = 0; kb < 4; ++kb) {
    __syncthreads();  // previous chunk fully consumed before overwrite
    #pragma unroll
    for (int j = 0; j < 4; ++j) {
      int g = j * 256 + wid * 64 + lane;  // 0..1023
      int row = g >> 3;                   // 0..127
      int sl = (g & 7) ^ (row & 7);       // pre-swizzled 16B segment
      const unsigned short* ga = img_bf + (size_t)(R0 + row) * DD + kb * 64 + sl * 8;
      const unsigned short* gb = con_bf + (size_t)(w0 + row) * DD + kb * 64 + sl * 8;
      unsigned char* la = ldsA + (j * 256 + wid * 64) * 16;  // wave-uniform
      unsigned char* lb = ldsB + (j * 256 + wid * 64) * 16;
      __builtin_amdgcn_global_load_lds(
          (const __attribute__((address_space(1))) unsigned int*)ga,
          (__attribute__((address_space(3))) unsigned int*)la, 16, 0, 0);
      __builtin_amdgcn_global_load_lds(
          (const __attribute__((address_space(1))) unsigned int*)gb,
          (__attribute__((address_space(3))) unsigned int*)lb, 16, 0, 0);
    }
    __syncthreads();  // compiler drains vmcnt(0) before the barrier
    #pragma unroll
    for (int kk = 0; kk < 2; ++kk) {
      bf16x8 af[4], bfr[4];
      int sw = ((((kk << 2) | q) ^ (r & 7)) << 4);
      #pragma unroll
      for (int pi = 0; pi < 4; ++pi) {
        int arow = wp * 64 + pi * 16 + r;
        af[pi] = *(const bf16x8*)(ldsA + arow * 128 + sw);
      }
      #pragma unroll
      for (int wj = 0; wj < 4; ++wj) {
        int brow = wc * 64 + wj * 16 + r;
        bfr[wj] = *(const bf16x8*)(ldsB + brow * 128 + sw);
      }
      #pragma unroll
      for (int pi = 0; pi < 4; ++pi)
        #pragma unroll
        for (int wj = 0; wj < 4; ++wj)
          acc[pi][wj] =
              __builtin_amdgcn_mfma_f32_16x16x32_bf16(af[pi], bfr[wj], acc[pi][wj], 0, 0, 0);
    }
  }

  // Epilogue: max over this wave's 64 rows for each of its 64 cols.
  float mxw[4];
  #pragma unroll
  for (int wj = 0; wj < 4; ++wj) {
    float v = -1e30f;
    #pragma unroll
    for (int pi = 0; pi < 4; ++pi) {
      v = fmaxf(v, fmaxf(fmaxf(acc[pi][wj][0], acc[pi][wj][1]),
                         fmaxf(acc[pi][wj][2], acc[pi][wj][3])));
    }
    v = fmaxf(v, __shfl_xor(v, 16));
    v = fmaxf(v, __shfl_xor(v, 32));
    mxw[wj] = v;
  }
  __syncthreads();
  if (lane < 16) {
    #pragma unroll
    for (int wj = 0; wj < 4; ++wj)
      sm[wp * 128 + wc * 64 + wj * 16 + lane] = mxw[wj];
  }
  __syncthreads();
  if (tid < 128) {
    int i0 = (2 * bm) / 9;                 // image of rows [R0, R0+64)
    int slot = bm - (9 * i0) / 2;          // tile slot within image i0 (0..4)
    bool crossing = ((2 * bm) % 9) == 8;   // boundary at local row 64
    float vlo = sm[tid];                   // rows 0..63  -> image i0
    float vhi = sm[128 + tid];             // rows 64..127 -> i0 or i0+1
    if (crossing) {
      P[(size_t)(i0 * 5 + slot) * 1024 + w0 + tid] = vlo;       // slot==4 here
      P[(size_t)((i0 + 1) * 5) * 1024 + w0 + tid] = vhi;        // slot 0 of i0+1
    } else {
      P[(size_t)(i0 * 5 + slot) * 1024 + w0 + tid] = fmaxf(vlo, vhi);
    }
  }
}

// Fused kernel C+D: 32 blocks, one image each. Each wave handles 8 (m,c)
// pairs sequentially with the EXACT per-pair arithmetic of the old kernel C
// (same fmax chain over 5 slots, same 32-lane shfl_xor sum tree, same /len),
// so sims is bit-identical. The last-arriving block (device-scope counter,
// release/acquire fences -> buffer_wbl2/inv give cross-XCD visibility) then
// runs the old kernel-D body verbatim. Only 32 blocks -> 128 wave-fences
// total (the round-2 version had 1024; suspected fence storm).
__global__ __launch_bounds__(256) void reduce_loss_kernel(
    const float* __restrict__ P, const int* __restrict__ lengths,
    const float* __restrict__ lscale, const float* __restrict__ lbias,
    float* __restrict__ sims, int* __restrict__ cnt, float* __restrict__ out) {
  int tid = threadIdx.x;
  int lane = tid & 63;
  int wv = tid >> 6;       // wave 0..3
  int m = blockIdx.x;      // image 0..31
  int w = lane & 31;
  #pragma unroll
  for (int i = 0; i < 8; ++i) {
    int c = wv * 8 + i;    // concept-sample 0..31
    const float* base = P + (size_t)(m * 5) * 1024 + c * 32 + w;
    float v = base[0];
    v = fmaxf(v, base[1024]);
    v = fmaxf(v, base[2048]);
    v = fmaxf(v, base[3072]);
    v = fmaxf(v, base[4096]);
    int len = lengths[c];
    float contrib = (w < len) ? v : 0.0f;
    #pragma unroll
    for (int off = 1; off < 32; off <<= 1) contrib += __shfl_xor(contrib, off);
    if (lane == 0) sims[m * 32 + c] = contrib / (float)len;
  }

  // --- last-block loss fold ---
  __threadfence();   // release our sims writes to device scope
  __syncthreads();   // all 32 pairs of this block written
  __shared__ int lastflag;
  if (tid == 0) lastflag = (atomicAdd(cnt, 1) == gridDim.x - 1) ? 1 : 0;
  __syncthreads();
  if (!lastflag) return;
  __threadfence();   // acquire: make all blocks' sims visible

  float tt = expf(fminf(fmaxf(lscale[0], -10.0f), 10.0f));
  float bias = lbias[0];
  float acc = 0.0f;
  for (int p = tid; p < BB * BB; p += 256) {
    int mm = p >> 5;
    int cc = p & 31;
    float lg = fminf(fmaxf(tt * sims[p] + bias, -50.0f), 50.0f);
    float x = (mm == cc) ? lg : -lg;
    float ls = (x >= 0.0f) ? -log1pf(expf(-x)) : (x - log1pf(expf(x)));
    acc += ls;
  }
  #pragma unroll
  for (int off = 1; off < 64; off <<= 1) acc += __shfl_xor(acc, off);
  __shared__ float s[4];
  if ((tid & 63) == 0) s[tid >> 6] = acc;
  __syncthreads();
  if (tid == 0) out[0] = -(s[0] + s[1] + s[2] + s[3]) / (float)(BB * BB);
}

extern "C" void kernel_launch(void* const* d_in, const int* in_sizes, int n_in,
                              void* d_out, int out_size, void* d_ws, size_t ws_size,
                              hipStream_t stream) {
  const float* img = (const float*)d_in[0];  // (32, 576, 256) f32
  const float* con = (const float*)d_in[1];  // (32, 32, 256) f32
  const int* lens = (const int*)d_in[2];     // (32,) i32
  const float* lsc = (const float*)d_in[3];  // (1,)
  const float* lbi = (const float*)d_in[4];  // (1,)

  unsigned short* img_bf = (unsigned short*)d_ws;              // 18432*256 bf16
  unsigned short* con_bf = img_bf + (size_t)BB * NP * DD;      // 1024*256 bf16
  float* P = (float*)(con_bf + (size_t)BB * WW * DD);          // 160*1024 f32
  float* sims = P + (size_t)160 * 1024;                        // 1024 f32
  int* cnt = (int*)(sims + 1024);                              // 1 i32

  norm_cast_kernel<<<(BB * NP + BB * WW) / 4, 256, 0, stream>>>(img, con, img_bf, con_bf, cnt);
  gemm_max_kernel<<<144 * 8, 256, 0, stream>>>(img_bf, con_bf, P);
  reduce_loss_kernel<<<32, 256, 0, stream>>>(P, lens, lsc, lbi, sims, cnt, (float*)d_out);
}

// Round 4
// 98.800 us; speedup vs baseline: 1.1311x; 1.0538x over previous
//
#include <hip/hip_runtime.h>
#include <hip/hip_bf16.h>
#include <math.h>

#define BB 32
#define NP 576
#define WW 32
#define DD 256
// GEMM view: M = 32*576 = 18432, N = 32*32 = 1024, K = 256.
// M is tiled as 144 contiguous 128-row tiles (image boundaries handled in the
// epilogue: gcd(128,576)=64 so a crossing tile always splits at local row 64,
// i.e. exactly at the wp wave split). N-tiles: 8 x 128.
//
// Round-3 lesson: __threadfence() (device scope) lowers to buffer_wbl2/inv =
// full L2 writeback per wave (~+9 us for 128 wave-fences). This version fuses
// C+D with a FENCE-FREE handoff: sims written via agent-scope (sc1,
// write-through) atomic stores that land at the point of coherence, ordering
// by s_waitcnt vmcnt(0) only, last-arriving block reads sims via agent-scope
// (cache-bypassing) atomic loads. No cache-maintenance instructions at all.

typedef __bf16 bf16x8 __attribute__((ext_vector_type(8)));
typedef float f32x4 __attribute__((ext_vector_type(4)));

__device__ __forceinline__ unsigned short f2bf(float f) {
  unsigned int u = __float_as_uint(f);
  u += 0x7FFFu + ((u >> 16) & 1u);
  return (unsigned short)(u >> 16);
}

// Kernel A: fused L2-normalize + bf16 cast. One wave per row of 256 floats.
// Also zeroes the completion counter used by the fused reduce+loss kernel
// (stream order guarantees this lands before that kernel runs).
__global__ __launch_bounds__(256) void norm_cast_kernel(
    const float* __restrict__ img, const float* __restrict__ con,
    unsigned short* __restrict__ img_bf, unsigned short* __restrict__ con_bf,
    int* __restrict__ cnt) {
  if (blockIdx.x == 0 && threadIdx.x == 0) *cnt = 0;
  int row = blockIdx.x * 4 + (threadIdx.x >> 6);
  int lane = threadIdx.x & 63;
  const int n_img = BB * NP;  // 18432 rows
  const float* src;
  unsigned short* dst;
  if (row < n_img) {
    src = img + (size_t)row * DD;
    dst = img_bf + (size_t)row * DD;
  } else {
    int r2 = row - n_img;
    src = con + (size_t)r2 * DD;
    dst = con_bf + (size_t)r2 * DD;
  }
  float4 v = ((const float4*)src)[lane];
  float ss = v.x * v.x + v.y * v.y + v.z * v.z + v.w * v.w;
  #pragma unroll
  for (int off = 1; off < 64; off <<= 1) ss += __shfl_xor(ss, off);
  float inv = 1.0f / fmaxf(sqrtf(ss), 1e-12f);
  ushort4 o;
  o.x = f2bf(v.x * inv);
  o.y = f2bf(v.y * inv);
  o.z = f2bf(v.z * inv);
  o.w = f2bf(v.w * inv);
  ((ushort4*)dst)[lane] = o;
}

// Kernel B: 128x128-tile GEMM (K=256, BK=64) with fused max-over-rows epilogue.
// EXACT round-1 version (proven). Staging via global_load_lds width=16 with
// pre-swizzled global source (m173 pattern); ds_read side conflict-free.
//   A-frag: lane(q=lane>>4, r=lane&15) holds A[row=r][k=q*8+j]
//   D-frag: lane holds D[row=q*4+reg][col=r]
__global__ __launch_bounds__(256, 3) void gemm_max_kernel(
    const unsigned short* __restrict__ img_bf,  // 18432 x 256
    const unsigned short* __restrict__ con_bf,  // 1024 x 256
    float* __restrict__ P) {                    // [160][1024] partial maxes
  int bx = blockIdx.x;
  int bw = bx & 7;    // N-tile 0..7
  int bm = bx >> 3;   // M-tile 0..143
  int R0 = bm * 128;  // global row base (all 128 rows valid)
  int w0 = bw * 128;

  __shared__ __align__(16) unsigned char lds[33 * 1024];
  unsigned char* ldsA = lds;            // 16 KB
  unsigned char* ldsB = lds + 16384;    // 16 KB
  float* sm = (float*)(lds + 32768);    // 2 x 128 floats

  int tid = threadIdx.x;
  int wid = tid >> 6;
  int lane = tid & 63;
  int q = lane >> 4;   // 0..3
  int r = lane & 15;   // 0..15
  int wp = wid >> 1;   // row-half 0..1 (64 rows each)
  int wc = wid & 1;    // col-half 0..1 (64 cols each)

  f32x4 acc[4][4];
  #pragma unroll
  for (int i = 0; i < 4; ++i)
    #pragma unroll
    for (int j = 0; j < 4; ++j) acc[i][j] = (f32x4){0.f, 0.f, 0.f, 0.f};

  for (int kb = 0; kb < 4; ++kb) {
    __syncthreads();  // previous chunk fully consumed before overwrite
    #pragma unroll
    for (int j = 0; j < 4; ++j) {
      int g = j * 256 + wid * 64 + lane;  // 0..1023
      int row = g >> 3;                   // 0..127
      int sl = (g & 7) ^ (row & 7);       // pre-swizzled 16B segment
      const unsigned short* ga = img_bf + (size_t)(R0 + row) * DD + kb * 64 + sl * 8;
      const unsigned short* gb = con_bf + (size_t)(w0 + row) * DD + kb * 64 + sl * 8;
      unsigned char* la = ldsA + (j * 256 + wid * 64) * 16;  // wave-uniform
      unsigned char* lb = ldsB + (j * 256 + wid * 64) * 16;
      __builtin_amdgcn_global_load_lds(
          (const __attribute__((address_space(1))) unsigned int*)ga,
          (__attribute__((address_space(3))) unsigned int*)la, 16, 0, 0);
      __builtin_amdgcn_global_load_lds(
          (const __attribute__((address_space(1))) unsigned int*)gb,
          (__attribute__((address_space(3))) unsigned int*)lb, 16, 0, 0);
    }
    __syncthreads();  // compiler drains vmcnt(0) before the barrier
    #pragma unroll
    for (int kk = 0; kk < 2; ++kk) {
      bf16x8 af[4], bfr[4];
      int sw = ((((kk << 2) | q) ^ (r & 7)) << 4);
      #pragma unroll
      for (int pi = 0; pi < 4; ++pi) {
        int arow = wp * 64 + pi * 16 + r;
        af[pi] = *(const bf16x8*)(ldsA + arow * 128 + sw);
      }
      #pragma unroll
      for (int wj = 0; wj < 4; ++wj) {
        int brow = wc * 64 + wj * 16 + r;
        bfr[wj] = *(const bf16x8*)(ldsB + brow * 128 + sw);
      }
      #pragma unroll
      for (int pi = 0; pi < 4; ++pi)
        #pragma unroll
        for (int wj = 0; wj < 4; ++wj)
          acc[pi][wj] =
              __builtin_amdgcn_mfma_f32_16x16x32_bf16(af[pi], bfr[wj], acc[pi][wj], 0, 0, 0);
    }
  }

  // Epilogue: max over this wave's 64 rows for each of its 64 cols.
  float mxw[4];
  #pragma unroll
  for (int wj = 0; wj < 4; ++wj) {
    float v = -1e30f;
    #pragma unroll
    for (int pi = 0; pi < 4; ++pi) {
      v = fmaxf(v, fmaxf(fmaxf(acc[pi][wj][0], acc[pi][wj][1]),
                         fmaxf(acc[pi][wj][2], acc[pi][wj][3])));
    }
    v = fmaxf(v, __shfl_xor(v, 16));
    v = fmaxf(v, __shfl_xor(v, 32));
    mxw[wj] = v;
  }
  __syncthreads();
  if (lane < 16) {
    #pragma unroll
    for (int wj = 0; wj < 4; ++wj)
      sm[wp * 128 + wc * 64 + wj * 16 + lane] = mxw[wj];
  }
  __syncthreads();
  if (tid < 128) {
    int i0 = (2 * bm) / 9;                 // image of rows [R0, R0+64)
    int slot = bm - (9 * i0) / 2;          // tile slot within image i0 (0..4)
    bool crossing = ((2 * bm) % 9) == 8;   // boundary at local row 64
    float vlo = sm[tid];                   // rows 0..63  -> image i0
    float vhi = sm[128 + tid];             // rows 64..127 -> i0 or i0+1
    if (crossing) {
      P[(size_t)(i0 * 5 + slot) * 1024 + w0 + tid] = vlo;       // slot==4 here
      P[(size_t)((i0 + 1) * 5) * 1024 + w0 + tid] = vhi;        // slot 0 of i0+1
    } else {
      P[(size_t)(i0 * 5 + slot) * 1024 + w0 + tid] = fmaxf(vlo, vhi);
    }
  }
}

// Fused C+D, FENCE-FREE: 32 blocks, one image each; per-pair arithmetic
// byte-identical to the proven kernel C (fmax chain over 5 slots, 5-level
// 32-lane shfl_xor butterfly, /len). sims written with agent-scope relaxed
// atomic stores (sc1, land at point of coherence, no L2 dirty lines).
// Ordering: s_waitcnt vmcnt(0) per wave, then __syncthreads, then one relaxed
// agent fetch_add; the block that draws ticket 31 sees all other blocks'
// stores already at the coherent point (their waitcnt preceded their ticket)
// and reads sims with cache-bypassing agent loads. No buffer_wbl2/inv.
__global__ __launch_bounds__(256) void reduce_loss_kernel(
    const float* __restrict__ P, const int* __restrict__ lengths,
    const float* __restrict__ lscale, const float* __restrict__ lbias,
    float* __restrict__ sims, int* __restrict__ cnt, float* __restrict__ out) {
  int tid = threadIdx.x;
  int lane = tid & 63;
  int wv = tid >> 6;       // wave 0..3
  int m = blockIdx.x;      // image 0..31
  int w = lane & 31;
  #pragma unroll
  for (int i = 0; i < 8; ++i) {
    int c = wv * 8 + i;    // concept-sample 0..31
    const float* base = P + (size_t)(m * 5) * 1024 + c * 32 + w;
    float v = base[0];
    v = fmaxf(v, base[1024]);
    v = fmaxf(v, base[2048]);
    v = fmaxf(v, base[3072]);
    v = fmaxf(v, base[4096]);
    int len = lengths[c];
    float contrib = (w < len) ? v : 0.0f;
    #pragma unroll
    for (int off = 1; off < 32; off <<= 1) contrib += __shfl_xor(contrib, off);
    if (lane == 0)
      __hip_atomic_store(&sims[m * 32 + c], contrib / (float)len,
                         __ATOMIC_RELAXED, __HIP_MEMORY_SCOPE_AGENT);
  }

  // --- fence-free last-block handoff ---
  asm volatile("s_waitcnt vmcnt(0)" ::: "memory");  // this wave's sims stores
                                                    // are at the coherent point
  __syncthreads();                                  // => whole block's are
  __shared__ int lastflag;
  if (tid == 0)
    lastflag = (__hip_atomic_fetch_add(cnt, 1, __ATOMIC_RELAXED,
                                       __HIP_MEMORY_SCOPE_AGENT) ==
                (int)gridDim.x - 1)
                   ? 1
                   : 0;
  __syncthreads();
  if (!lastflag) return;

  // Last block: fold the loss (old kernel-D body; sims via agent loads).
  float tt = expf(fminf(fmaxf(lscale[0], -10.0f), 10.0f));
  float bias = lbias[0];
  float acc = 0.0f;
  for (int p = tid; p < BB * BB; p += 256) {
    int mm = p >> 5;
    int cc = p & 31;
    float sv = __hip_atomic_load(&sims[p], __ATOMIC_RELAXED,
                                 __HIP_MEMORY_SCOPE_AGENT);
    float lg = fminf(fmaxf(tt * sv + bias, -50.0f), 50.0f);
    float x = (mm == cc) ? lg : -lg;
    float ls = (x >= 0.0f) ? -log1pf(expf(-x)) : (x - log1pf(expf(x)));
    acc += ls;
  }
  #pragma unroll
  for (int off = 1; off < 64; off <<= 1) acc += __shfl_xor(acc, off);
  __shared__ float s[4];
  if ((tid & 63) == 0) s[tid >> 6] = acc;
  __syncthreads();
  if (tid == 0) out[0] = -(s[0] + s[1] + s[2] + s[3]) / (float)(BB * BB);
}

extern "C" void kernel_launch(void* const* d_in, const int* in_sizes, int n_in,
                              void* d_out, int out_size, void* d_ws, size_t ws_size,
                              hipStream_t stream) {
  const float* img = (const float*)d_in[0];  // (32, 576, 256) f32
  const float* con = (const float*)d_in[1];  // (32, 32, 256) f32
  const int* lens = (const int*)d_in[2];     // (32,) i32
  const float* lsc = (const float*)d_in[3];  // (1,)
  const float* lbi = (const float*)d_in[4];  // (1,)

  unsigned short* img_bf = (unsigned short*)d_ws;              // 18432*256 bf16
  unsigned short* con_bf = img_bf + (size_t)BB * NP * DD;      // 1024*256 bf16
  float* P = (float*)(con_bf + (size_t)BB * WW * DD);          // 160*1024 f32
  float* sims = P + (size_t)160 * 1024;                        // 1024 f32
  int* cnt = (int*)(sims + 1024);                              // 1 i32

  norm_cast_kernel<<<(BB * NP + BB * WW) / 4, 256, 0, stream>>>(img, con, img_bf, con_bf, cnt);
  gemm_max_kernel<<<144 * 8, 256, 0, stream>>>(img_bf, con_bf, P);
  reduce_loss_kernel<<<32, 256, 0, stream>>>(P, lens, lsc, lbi, sims, cnt, (float*)d_out);
}

// Round 5
// 98.575 us; speedup vs baseline: 1.1337x; 1.0023x over previous
//
#include <hip/hip_runtime.h>
#include <hip/hip_bf16.h>
#include <math.h>

#define BB 32
#define NP 576
#define WW 32
#define DD 256
// GEMM view: M = 32*576 = 18432, N = 32*32 = 1024, K = 256.
// M is tiled as 144 contiguous 128-row tiles (image boundaries handled in the
// epilogue: gcd(128,576)=64 so a crossing tile always splits at local row 64,
// i.e. exactly at the wp wave split). N-tiles: 8 x 128.
//
// Round-4 lessons: (a) launches are graph-captured, ~1-2 us each -> kernel
// fusion buys nothing (R3 fence version +9, R4 fence-free version +3.7 vs
// separate kernels). C/D stay separate (R1 proven form). (b) By subtraction,
// GEMM B is ~30 us (~320 TF): the single-buffered K-loop exposes a full
// global->LDS latency every K-step. This version: BK=32 double-buffered with
// prefetch-before-compute (T3 minimal 2-phase), one barrier per step, LDS
// unchanged at 33 KB -> occupancy stays 3 blocks/CU.

typedef __bf16 bf16x8 __attribute__((ext_vector_type(8)));
typedef float f32x4 __attribute__((ext_vector_type(4)));

__device__ __forceinline__ unsigned short f2bf(float f) {
  unsigned int u = __float_as_uint(f);
  u += 0x7FFFu + ((u >> 16) & 1u);
  return (unsigned short)(u >> 16);
}

// Kernel A: fused L2-normalize + bf16 cast. One wave per row of 256 floats.
__global__ __launch_bounds__(256) void norm_cast_kernel(
    const float* __restrict__ img, const float* __restrict__ con,
    unsigned short* __restrict__ img_bf, unsigned short* __restrict__ con_bf) {
  int row = blockIdx.x * 4 + (threadIdx.x >> 6);
  int lane = threadIdx.x & 63;
  const int n_img = BB * NP;  // 18432 rows
  const float* src;
  unsigned short* dst;
  if (row < n_img) {
    src = img + (size_t)row * DD;
    dst = img_bf + (size_t)row * DD;
  } else {
    int r2 = row - n_img;
    src = con + (size_t)r2 * DD;
    dst = con_bf + (size_t)r2 * DD;
  }
  float4 v = ((const float4*)src)[lane];
  float ss = v.x * v.x + v.y * v.y + v.z * v.z + v.w * v.w;
  #pragma unroll
  for (int off = 1; off < 64; off <<= 1) ss += __shfl_xor(ss, off);
  float inv = 1.0f / fmaxf(sqrtf(ss), 1e-12f);
  ushort4 o;
  o.x = f2bf(v.x * inv);
  o.y = f2bf(v.y * inv);
  o.z = f2bf(v.z * inv);
  o.w = f2bf(v.w * inv);
  ((ushort4*)dst)[lane] = o;
}

// Kernel B: 128x128-tile GEMM, K=256 as 8 steps of BK=32, double-buffered LDS
// with prefetch-before-compute; fused max-over-rows epilogue.
// LDS per matrix per buffer: 128 rows x 64 B (4 x 16B segments). Swizzle:
// LDS slot (row, seg) holds global segment seg ^ ((row>>1)&3). This makes
// each aligned 8-lane group of the ds_read_b128 fragment reads cover all 8
// 16B bank-chunks (conflict-free), and is applied on the PRE-SWIZZLED GLOBAL
// SOURCE with a linear wave-uniform LDS destination (global_load_lds rule).
// Fragment layouts unchanged from the proven round-1 kernel:
//   A-frag: lane(q=lane>>4, r=lane&15) holds A[row=r][k=q*8+j]
//   D-frag: lane holds D[row=q*4+reg][col=r]
// Accumulation order over K is identical to round 1 (same 8 K=32 chunks in
// the same order) -> bit-identical results.
__global__ __launch_bounds__(256, 3) void gemm_max_kernel(
    const unsigned short* __restrict__ img_bf,  // 18432 x 256
    const unsigned short* __restrict__ con_bf,  // 1024 x 256
    float* __restrict__ P) {                    // [160][1024] partial maxes
  int bx = blockIdx.x;
  int bw = bx & 7;    // N-tile 0..7
  int bm = bx >> 3;   // M-tile 0..143
  int R0 = bm * 128;  // global row base (all 128 rows valid)
  int w0 = bw * 128;

  __shared__ __align__(16) unsigned char lds[33 * 1024];
  unsigned char* ldsA = lds;            // 2 bufs x 8 KB (offsets 0, 8192)
  unsigned char* ldsB = lds + 16384;    // 2 bufs x 8 KB
  float* sm = (float*)(lds + 32768);    // 2 x 128 floats

  int tid = threadIdx.x;
  int wid = tid >> 6;
  int lane = tid & 63;
  int q = lane >> 4;   // 0..3
  int r = lane & 15;   // 0..15
  int wp = wid >> 1;   // row-half 0..1 (64 rows each)
  int wc = wid & 1;    // col-half 0..1 (64 cols each)

  f32x4 acc[4][4];
  #pragma unroll
  for (int i = 0; i < 4; ++i)
    #pragma unroll
    for (int j = 0; j < 4; ++j) acc[i][j] = (f32x4){0.f, 0.f, 0.f, 0.f};

  // Stage one BK=32 chunk of A and B into buffer `buf`.
  // 512 x 16B slots per matrix; 256 threads x 2 slots each.
  auto stage = [&](int buf, int kb) {
    #pragma unroll
    for (int j = 0; j < 2; ++j) {
      int g = j * 256 + wid * 64 + lane;  // 0..511
      int row = g >> 2;                   // 0..127
      int sl = (g & 3) ^ ((row >> 1) & 3);  // pre-swizzled 16B segment
      const unsigned short* ga = img_bf + (size_t)(R0 + row) * DD + kb * 32 + sl * 8;
      const unsigned short* gb = con_bf + (size_t)(w0 + row) * DD + kb * 32 + sl * 8;
      unsigned char* la = ldsA + buf * 8192 + (j * 256 + wid * 64) * 16;  // wave-uniform
      unsigned char* lb = ldsB + buf * 8192 + (j * 256 + wid * 64) * 16;
      __builtin_amdgcn_global_load_lds(
          (const __attribute__((address_space(1))) unsigned int*)ga,
          (__attribute__((address_space(3))) unsigned int*)la, 16, 0, 0);
      __builtin_amdgcn_global_load_lds(
          (const __attribute__((address_space(1))) unsigned int*)gb,
          (__attribute__((address_space(3))) unsigned int*)lb, 16, 0, 0);
    }
  };

  stage(0, 0);
  __syncthreads();  // drain prologue loads (vmcnt(0) implicit in barrier)
  for (int kb = 0; kb < 8; ++kb) {
    int cur = kb & 1;
    // Prefetch next chunk into the other buffer (its readers finished at the
    // barrier ending step kb-1), then compute current while loads fly.
    if (kb < 7) stage(cur ^ 1, kb + 1);
    bf16x8 af[4], bfr[4];
    #pragma unroll
    for (int pi = 0; pi < 4; ++pi) {
      int arow = wp * 64 + pi * 16 + r;
      af[pi] = *(const bf16x8*)(ldsA + cur * 8192 + arow * 64 +
                                ((q ^ ((arow >> 1) & 3)) << 4));
    }
    #pragma unroll
    for (int wj = 0; wj < 4; ++wj) {
      int brow = wc * 64 + wj * 16 + r;
      bfr[wj] = *(const bf16x8*)(ldsB + cur * 8192 + brow * 64 +
                                 ((q ^ ((brow >> 1) & 3)) << 4));
    }
    #pragma unroll
    for (int pi = 0; pi < 4; ++pi)
      #pragma unroll
      for (int wj = 0; wj < 4; ++wj)
        acc[pi][wj] =
            __builtin_amdgcn_mfma_f32_16x16x32_bf16(af[pi], bfr[wj], acc[pi][wj], 0, 0, 0);
    __syncthreads();  // waits prefetch (had compute-time to fly) + read-done
  }

  // Epilogue: max over this wave's 64 rows for each of its 64 cols.
  float mxw[4];
  #pragma unroll
  for (int wj = 0; wj < 4; ++wj) {
    float v = -1e30f;
    #pragma unroll
    for (int pi = 0; pi < 4; ++pi) {
      v = fmaxf(v, fmaxf(fmaxf(acc[pi][wj][0], acc[pi][wj][1]),
                         fmaxf(acc[pi][wj][2], acc[pi][wj][3])));
    }
    v = fmaxf(v, __shfl_xor(v, 16));
    v = fmaxf(v, __shfl_xor(v, 32));
    mxw[wj] = v;
  }
  if (lane < 16) {
    #pragma unroll
    for (int wj = 0; wj < 4; ++wj)
      sm[wp * 128 + wc * 64 + wj * 16 + lane] = mxw[wj];
  }
  __syncthreads();
  if (tid < 128) {
    int i0 = (2 * bm) / 9;                 // image of rows [R0, R0+64)
    int slot = bm - (9 * i0) / 2;          // tile slot within image i0 (0..4)
    bool crossing = ((2 * bm) % 9) == 8;   // boundary at local row 64
    float vlo = sm[tid];                   // rows 0..63  -> image i0
    float vhi = sm[128 + tid];             // rows 64..127 -> i0 or i0+1
    if (crossing) {
      P[(size_t)(i0 * 5 + slot) * 1024 + w0 + tid] = vlo;       // slot==4 here
      P[(size_t)((i0 + 1) * 5) * 1024 + w0 + tid] = vhi;        // slot 0 of i0+1
    } else {
      P[(size_t)(i0 * 5 + slot) * 1024 + w0 + tid] = fmaxf(vlo, vhi);
    }
  }
}

// Kernel C: reduce partial maxes over the 5 tile-slots of each image, masked
// mean over valid concepts -> sims. (Round-1 proven form, separate kernels.)
__global__ __launch_bounds__(256) void reduce_kernel(
    const float* __restrict__ P, const int* __restrict__ lengths,
    float* __restrict__ sims) {
  int pair = blockIdx.x * 4 + (threadIdx.x >> 6);  // 0..1023
  int lane = threadIdx.x & 63;
  int m = pair >> 5;
  int c = pair & 31;
  int w = lane & 31;
  const float* base = P + (size_t)(m * 5) * 1024 + c * 32 + w;
  float v = base[0];
  v = fmaxf(v, base[1024]);
  v = fmaxf(v, base[2048]);
  v = fmaxf(v, base[3072]);
  v = fmaxf(v, base[4096]);
  int len = lengths[c];
  float contrib = (w < len) ? v : 0.0f;
  #pragma unroll
  for (int off = 1; off < 32; off <<= 1) contrib += __shfl_xor(contrib, off);
  if (lane == 0) sims[pair] = contrib / (float)len;
}

// Kernel D: fold 1024 sims into the SigLIP-style loss.
__global__ __launch_bounds__(256) void loss_kernel(
    const float* __restrict__ sims, const float* __restrict__ lscale,
    const float* __restrict__ lbias, float* __restrict__ out) {
  float tt = expf(fminf(fmaxf(lscale[0], -10.0f), 10.0f));
  float bias = lbias[0];
  int tid = threadIdx.x;
  float acc = 0.0f;
  for (int p = tid; p < BB * BB; p += 256) {
    int mm = p >> 5;
    int cc = p & 31;
    float lg = fminf(fmaxf(tt * sims[p] + bias, -50.0f), 50.0f);
    float x = (mm == cc) ? lg : -lg;
    float ls = (x >= 0.0f) ? -log1pf(expf(-x)) : (x - log1pf(expf(x)));
    acc += ls;
  }
  #pragma unroll
  for (int off = 1; off < 64; off <<= 1) acc += __shfl_xor(acc, off);
  __shared__ float s[4];
  if ((tid & 63) == 0) s[tid >> 6] = acc;
  __syncthreads();
  if (tid == 0) out[0] = -(s[0] + s[1] + s[2] + s[3]) / (float)(BB * BB);
}

extern "C" void kernel_launch(void* const* d_in, const int* in_sizes, int n_in,
                              void* d_out, int out_size, void* d_ws, size_t ws_size,
                              hipStream_t stream) {
  const float* img = (const float*)d_in[0];  // (32, 576, 256) f32
  const float* con = (const float*)d_in[1];  // (32, 32, 256) f32
  const int* lens = (const int*)d_in[2];     // (32,) i32
  const float* lsc = (const float*)d_in[3];  // (1,)
  const float* lbi = (const float*)d_in[4];  // (1,)

  unsigned short* img_bf = (unsigned short*)d_ws;              // 18432*256 bf16
  unsigned short* con_bf = img_bf + (size_t)BB * NP * DD;      // 1024*256 bf16
  float* P = (float*)(con_bf + (size_t)BB * WW * DD);          // 160*1024 f32
  float* sims = P + (size_t)160 * 1024;                        // 1024 f32

  norm_cast_kernel<<<(BB * NP + BB * WW) / 4, 256, 0, stream>>>(img, con, img_bf, con_bf);
  gemm_max_kernel<<<144 * 8, 256, 0, stream>>>(img_bf, con_bf, P);
  reduce_kernel<<<256, 256, 0, stream>>>(P, lens, sims);
  loss_kernel<<<1, 256, 0, stream>>>(sims, lsc, lbi, (float*)d_out);
}

// Round 6
// 92.877 us; speedup vs baseline: 1.2033x; 1.0614x over previous
//
#include <hip/hip_runtime.h>
#include <hip/hip_bf16.h>
#include <math.h>

#define BB 32
#define NP 576
#define WW 32
#define DD 256
// GEMM view: M = 32*576 = 18432, N = 32*32 = 1024, K = 256.
// M is tiled as 144 contiguous 128-row tiles (image boundaries handled in the
// epilogue: gcd(128,576)=64 so a crossing tile always splits at local row 64,
// i.e. exactly at the wp wave split). N-tiles: 8 x 128.
//
// Round-5 theory: with bx = bm*8+bw and round-robin XCD dispatch (xcd=bx%8),
// the 8 blocks sharing an A-panel land on 8 DIFFERENT XCDs -> zero per-XCD L2
// reuse of A -> all 74 MB of A staging comes from L3/fabric (~2.5 TB/s
// effective) -> B is BW-bound (~30 us). Consistent with every intra-block
// lever (gload_lds R0, dbuf R5) measuring null. Fix (T1): XCD-chunked block
// swizzle swz=(bx&7)*144+(bx>>3); XCD x owns bm in [18x,18x+18) -> A working
// set 1.18 MB + con 0.5 MB fits the 4 MB per-XCD L2; L3 traffic 78 -> 14 MB.

typedef __bf16 bf16x8 __attribute__((ext_vector_type(8)));
typedef float f32x4 __attribute__((ext_vector_type(4)));

__device__ __forceinline__ unsigned short f2bf(float f) {
  unsigned int u = __float_as_uint(f);
  u += 0x7FFFu + ((u >> 16) & 1u);
  return (unsigned short)(u >> 16);
}

// Kernel A: fused L2-normalize + bf16 cast. One wave per row of 256 floats.
__global__ __launch_bounds__(256) void norm_cast_kernel(
    const float* __restrict__ img, const float* __restrict__ con,
    unsigned short* __restrict__ img_bf, unsigned short* __restrict__ con_bf) {
  int row = blockIdx.x * 4 + (threadIdx.x >> 6);
  int lane = threadIdx.x & 63;
  const int n_img = BB * NP;  // 18432 rows
  const float* src;
  unsigned short* dst;
  if (row < n_img) {
    src = img + (size_t)row * DD;
    dst = img_bf + (size_t)row * DD;
  } else {
    int r2 = row - n_img;
    src = con + (size_t)r2 * DD;
    dst = con_bf + (size_t)r2 * DD;
  }
  float4 v = ((const float4*)src)[lane];
  float ss = v.x * v.x + v.y * v.y + v.z * v.z + v.w * v.w;
  #pragma unroll
  for (int off = 1; off < 64; off <<= 1) ss += __shfl_xor(ss, off);
  float inv = 1.0f / fmaxf(sqrtf(ss), 1e-12f);
  ushort4 o;
  o.x = f2bf(v.x * inv);
  o.y = f2bf(v.y * inv);
  o.z = f2bf(v.z * inv);
  o.w = f2bf(v.w * inv);
  ((ushort4*)dst)[lane] = o;
}

// Kernel B: 128x128-tile GEMM (K=256, BK=64) with fused max-over-rows epilogue.
// EXACT round-1 interior (proven 95.1 us pipeline); the ONLY change is the
// XCD-chunked tile-index swizzle (see header comment). Staging via
// global_load_lds width=16 with pre-swizzled global source (m173 pattern);
// ds_read side conflict-free.
//   A-frag: lane(q=lane>>4, r=lane&15) holds A[row=r][k=q*8+j]
//   D-frag: lane holds D[row=q*4+reg][col=r]
__global__ __launch_bounds__(256, 3) void gemm_max_kernel(
    const unsigned short* __restrict__ img_bf,  // 18432 x 256
    const unsigned short* __restrict__ con_bf,  // 1024 x 256
    float* __restrict__ P) {                    // [160][1024] partial maxes
  int bx = blockIdx.x;
  // XCD-chunked swizzle: 1152 = 8 x 144 exactly -> bijective.
  // xcd = bx%8 (dispatch heuristic) gets contiguous tile range
  // [xcd*144, (xcd+1)*144): bw varies fastest -> 8 consecutive tiles share
  // one A-panel, all on the same XCD.
  int swz = (bx & 7) * 144 + (bx >> 3);
  int bw = swz & 7;    // N-tile 0..7
  int bm = swz >> 3;   // M-tile 0..143
  int R0 = bm * 128;   // global row base (all 128 rows valid)
  int w0 = bw * 128;

  __shared__ __align__(16) unsigned char lds[33 * 1024];
  unsigned char* ldsA = lds;            // 16 KB
  unsigned char* ldsB = lds + 16384;    // 16 KB
  float* sm = (float*)(lds + 32768);    // 2 x 128 floats

  int tid = threadIdx.x;
  int wid = tid >> 6;
  int lane = tid & 63;
  int q = lane >> 4;   // 0..3
  int r = lane & 15;   // 0..15
  int wp = wid >> 1;   // row-half 0..1 (64 rows each)
  int wc = wid & 1;    // col-half 0..1 (64 cols each)

  f32x4 acc[4][4];
  #pragma unroll
  for (int i = 0; i < 4; ++i)
    #pragma unroll
    for (int j = 0; j < 4; ++j) acc[i][j] = (f32x4){0.f, 0.f, 0.f, 0.f};

  for (int kb = 0; kb < 4; ++kb) {
    __syncthreads();  // previous chunk fully consumed before overwrite
    #pragma unroll
    for (int j = 0; j < 4; ++j) {
      int g = j * 256 + wid * 64 + lane;  // 0..1023
      int row = g >> 3;                   // 0..127
      int sl = (g & 7) ^ (row & 7);       // pre-swizzled 16B segment
      const unsigned short* ga = img_bf + (size_t)(R0 + row) * DD + kb * 64 + sl * 8;
      const unsigned short* gb = con_bf + (size_t)(w0 + row) * DD + kb * 64 + sl * 8;
      unsigned char* la = ldsA + (j * 256 + wid * 64) * 16;  // wave-uniform
      unsigned char* lb = ldsB + (j * 256 + wid * 64) * 16;
      __builtin_amdgcn_global_load_lds(
          (const __attribute__((address_space(1))) unsigned int*)ga,
          (__attribute__((address_space(3))) unsigned int*)la, 16, 0, 0);
      __builtin_amdgcn_global_load_lds(
          (const __attribute__((address_space(1))) unsigned int*)gb,
          (__attribute__((address_space(3))) unsigned int*)lb, 16, 0, 0);
    }
    __syncthreads();  // compiler drains vmcnt(0) before the barrier
    #pragma unroll
    for (int kk = 0; kk < 2; ++kk) {
      bf16x8 af[4], bfr[4];
      int sw = ((((kk << 2) | q) ^ (r & 7)) << 4);
      #pragma unroll
      for (int pi = 0; pi < 4; ++pi) {
        int arow = wp * 64 + pi * 16 + r;
        af[pi] = *(const bf16x8*)(ldsA + arow * 128 + sw);
      }
      #pragma unroll
      for (int wj = 0; wj < 4; ++wj) {
        int brow = wc * 64 + wj * 16 + r;
        bfr[wj] = *(const bf16x8*)(ldsB + brow * 128 + sw);
      }
      #pragma unroll
      for (int pi = 0; pi < 4; ++pi)
        #pragma unroll
        for (int wj = 0; wj < 4; ++wj)
          acc[pi][wj] =
              __builtin_amdgcn_mfma_f32_16x16x32_bf16(af[pi], bfr[wj], acc[pi][wj], 0, 0, 0);
    }
  }

  // Epilogue: max over this wave's 64 rows for each of its 64 cols.
  float mxw[4];
  #pragma unroll
  for (int wj = 0; wj < 4; ++wj) {
    float v = -1e30f;
    #pragma unroll
    for (int pi = 0; pi < 4; ++pi) {
      v = fmaxf(v, fmaxf(fmaxf(acc[pi][wj][0], acc[pi][wj][1]),
                         fmaxf(acc[pi][wj][2], acc[pi][wj][3])));
    }
    v = fmaxf(v, __shfl_xor(v, 16));
    v = fmaxf(v, __shfl_xor(v, 32));
    mxw[wj] = v;
  }
  __syncthreads();
  if (lane < 16) {
    #pragma unroll
    for (int wj = 0; wj < 4; ++wj)
      sm[wp * 128 + wc * 64 + wj * 16 + lane] = mxw[wj];
  }
  __syncthreads();
  if (tid < 128) {
    int i0 = (2 * bm) / 9;                 // image of rows [R0, R0+64)
    int slot = bm - (9 * i0) / 2;          // tile slot within image i0 (0..4)
    bool crossing = ((2 * bm) % 9) == 8;   // boundary at local row 64
    float vlo = sm[tid];                   // rows 0..63  -> image i0
    float vhi = sm[128 + tid];             // rows 64..127 -> i0 or i0+1
    if (crossing) {
      P[(size_t)(i0 * 5 + slot) * 1024 + w0 + tid] = vlo;       // slot==4 here
      P[(size_t)((i0 + 1) * 5) * 1024 + w0 + tid] = vhi;        // slot 0 of i0+1
    } else {
      P[(size_t)(i0 * 5 + slot) * 1024 + w0 + tid] = fmaxf(vlo, vhi);
    }
  }
}

// Kernel C: reduce partial maxes over the 5 tile-slots of each image, masked
// mean over valid concepts -> sims. (Round-1 proven form.)
__global__ __launch_bounds__(256) void reduce_kernel(
    const float* __restrict__ P, const int* __restrict__ lengths,
    float* __restrict__ sims) {
  int pair = blockIdx.x * 4 + (threadIdx.x >> 6);  // 0..1023
  int lane = threadIdx.x & 63;
  int m = pair >> 5;
  int c = pair & 31;
  int w = lane & 31;
  const float* base = P + (size_t)(m * 5) * 1024 + c * 32 + w;
  float v = base[0];
  v = fmaxf(v, base[1024]);
  v = fmaxf(v, base[2048]);
  v = fmaxf(v, base[3072]);
  v = fmaxf(v, base[4096]);
  int len = lengths[c];
  float contrib = (w < len) ? v : 0.0f;
  #pragma unroll
  for (int off = 1; off < 32; off <<= 1) contrib += __shfl_xor(contrib, off);
  if (lane == 0) sims[pair] = contrib / (float)len;
}

// Kernel D: fold 1024 sims into the SigLIP-style loss.
__global__ __launch_bounds__(256) void loss_kernel(
    const float* __restrict__ sims, const float* __restrict__ lscale,
    const float* __restrict__ lbias, float* __restrict__ out) {
  float tt = expf(fminf(fmaxf(lscale[0], -10.0f), 10.0f));
  float bias = lbias[0];
  int tid = threadIdx.x;
  float acc = 0.0f;
  for (int p = tid; p < BB * BB; p += 256) {
    int mm = p >> 5;
    int cc = p & 31;
    float lg = fminf(fmaxf(tt * sims[p] + bias, -50.0f), 50.0f);
    float x = (mm == cc) ? lg : -lg;
    float ls = (x >= 0.0f) ? -log1pf(expf(-x)) : (x - log1pf(expf(x)));
    acc += ls;
  }
  #pragma unroll
  for (int off = 1; off < 64; off <<= 1) acc += __shfl_xor(acc, off);
  __shared__ float s[4];
  if ((tid & 63) == 0) s[tid >> 6] = acc;
  __syncthreads();
  if (tid == 0) out[0] = -(s[0] + s[1] + s[2] + s[3]) / (float)(BB * BB);
}

extern "C" void kernel_launch(void* const* d_in, const int* in_sizes, int n_in,
                              void* d_out, int out_size, void* d_ws, size_t ws_size,
                              hipStream_t stream) {
  const float* img = (const float*)d_in[0];  // (32, 576, 256) f32
  const float* con = (const float*)d_in[1];  // (32, 32, 256) f32
  const int* lens = (const int*)d_in[2];     // (32,) i32
  const float* lsc = (const float*)d_in[3];  // (1,)
  const float* lbi = (const float*)d_in[4];  // (1,)

  unsigned short* img_bf = (unsigned short*)d_ws;              // 18432*256 bf16
  unsigned short* con_bf = img_bf + (size_t)BB * NP * DD;      // 1024*256 bf16
  float* P = (float*)(con_bf + (size_t)BB * WW * DD);          // 160*1024 f32
  float* sims = P + (size_t)160 * 1024;                        // 1024 f32

  norm_cast_kernel<<<(BB * NP + BB * WW) / 4, 256, 0, stream>>>(img, con, img_bf, con_bf);
  gemm_max_kernel<<<144 * 8, 256, 0, stream>>>(img_bf, con_bf, P);
  reduce_kernel<<<256, 256, 0, stream>>>(P, lens, sims);
  loss_kernel<<<1, 256, 0, stream>>>(sims, lsc, lbi, (float*)d_out);
}